// Round 5
// baseline (28385.889 us; speedup 1.0000x reference)
//
#include <hip/hip_runtime.h>

#define S_LEN 512
#define BATCH 128
#define NH    128
#define NL    3

#define HXS  392   // hx row stride (shorts)
#define INPS 136   // inp row stride (shorts)

// workspace layout (bytes)
#define XP_OFF   0u
#define WP_OFF   16777216u              // 384 frags * 1KB
#define UP_OFF   (WP_OFF + 393216u)     // 1152 frags * 1KB
#define HX_OFF   (UP_OFF + 1179648u)    // 2 par * 8 grp * 3 l * 16*128 bf16 = 196608
#define FLAG_OFF (HX_OFF + 196608u)     // 512*3*8 u32 = 49152
#define FLAG_SZ  49152u

typedef float f32x4 __attribute__((ext_vector_type(4)));
typedef short bf16x8 __attribute__((ext_vector_type(8)));

__device__ __forceinline__ short f2bf(float f) {
    unsigned u = __builtin_bit_cast(unsigned, f);
    u = (u + 0x7FFFu + ((u >> 16) & 1u)) >> 16;
    return (short)u;
}
__device__ __forceinline__ float bf2f(short s) {
    unsigned u = ((unsigned)(unsigned short)s) << 16;
    return __builtin_bit_cast(float, u);
}
__device__ __forceinline__ float bf2f_lo(unsigned u) { return __builtin_bit_cast(float, u << 16); }
__device__ __forceinline__ float bf2f_hi(unsigned u) { return __builtin_bit_cast(float, u & 0xFFFF0000u); }
__device__ __forceinline__ float sigm(float x) { return 1.f / (1.f + __expf(-x)); }
__device__ __forceinline__ float tanh_fast(float x) { return 2.f / (1.f + __expf(-2.f * x)) - 1.f; }

// ---------------- K1: xp = x @ lin_w.T + lin_b  ->  bf16 [S*B][H] ----------------
__global__ __launch_bounds__(128) void xp_kernel(const float* __restrict__ x,
        const float* __restrict__ lin_w, const float* __restrict__ lin_b,
        short* __restrict__ xp) {
    __shared__ float xs[8 * 128];
    const int tid = threadIdx.x;
    const long r0 = (long)blockIdx.x * 8;
    for (int rr = 0; rr < 8; ++rr)
        xs[rr * 128 + tid] = x[(r0 + rr) * 128 + tid];
    __syncthreads();
    float acc[8];
    float bias = lin_b[tid];
    #pragma unroll
    for (int rr = 0; rr < 8; ++rr) acc[rr] = bias;
    const float* wrow = lin_w + (long)tid * 128;
    for (int k = 0; k < 128; ++k) {
        float wv = wrow[k];
        #pragma unroll
        for (int rr = 0; rr < 8; ++rr) acc[rr] += xs[rr * 128 + k] * wv;
    }
    for (int rr = 0; rr < 8; ++rr)
        xp[(r0 + rr) * 128 + tid] = f2bf(acc[rr]);
}

// ---------------- K2: pack W,U per (unit, gate-wave) fragment-linear ----------------
// unit = l*8 + c  (c = 16-col h-chunk). Wave g of a unit owns rows g*128 + c*16 + [0,16).
// Fragment: lane(lr=lane&15, lk=lane>>4), elem j -> row base+lr, col kt*32 + lk*8 + j.
// Wp frag id = (unit*4+g)*4 + kt    [384]
// Up frag id = (unit*4+g)*12 + kt   [1152]
__global__ __launch_bounds__(256) void pack_kernel(const float* __restrict__ W,
        const float* __restrict__ U, short* __restrict__ Wp, short* __restrict__ Up) {
    int id = blockIdx.x * 256 + threadIdx.x;     // 98304 = 1536 frags * 64 lanes
    int lane = id & 63;
    int fid = id >> 6;
    int lr = lane & 15, lk = lane >> 4;
    if (fid < 384) {
        int kt = fid & 3, g = (fid >> 2) & 3, unit = fid >> 4;
        int l = unit >> 3, c = unit & 7;
        int row = g * 128 + c * 16 + lr;
        const float* src = W + ((long)(l * 512 + row)) * 128 + kt * 32 + lk * 8;
        short* dst = Wp + (long)fid * 512 + lane * 8;
        #pragma unroll
        for (int j = 0; j < 8; ++j) dst[j] = f2bf(src[j]);
    } else {
        int f = fid - 384;
        int kt = f % 12, gu = f / 12;
        int g = gu & 3, unit = gu >> 2;
        int l = unit >> 3, c = unit & 7;
        int row = g * 128 + c * 16 + lr;
        const float* src = U + ((long)(l * 512 + row)) * 384 + kt * 32 + lk * 8;
        short* dst = Up + (long)f * 512 + lane * 8;
        #pragma unroll
        for (int j = 0; j < 8; ++j) dst[j] = f2bf(src[j]);
    }
}

// ---------------- main: 192 WGs (24 units x 8 batch groups), weights in VGPRs ----------------
__global__ __launch_bounds__(256) void lstm_kernel(
    const short* __restrict__ xp, const short* __restrict__ Wp,
    const short* __restrict__ Up, const float* __restrict__ Gp,
    unsigned* __restrict__ hexch, unsigned* __restrict__ flags,
    float* __restrict__ out)
{
    __shared__ short hx_lds[16 * HXS];        // 12544 B
    __shared__ short inp_lds[16 * INPS];      //  4352 B
    __shared__ unsigned hraw[NL * 16 * 64];   // 12288 B (u32 view of h[3][16][128])
    __shared__ float gates_lds[4 * 16 * 17];  //  4352 B
    __shared__ float G_lds[NL * 128];         //  1536 B
    __shared__ float gh_lds[48];
    __shared__ short hsl[16 * 16];            //   512 B
    __shared__ int s_abort;

    const int tid  = threadIdx.x;
    const int lane = tid & 63;
    const int w    = tid >> 6;        // wave 0..3 = gate index (i,f,g,o)
    const int lr   = lane & 15;
    const int lk   = lane >> 4;
    const int grp  = blockIdx.x & 7;  // batch group (XCD-affine; perf only)
    const int unit = blockIdx.x >> 3; // 0..23
    const int l    = unit >> 3;       // owned layer
    const int c    = unit & 7;        // owned 16-col h-chunk
    const int b0   = grp * 16;
    const int bb   = tid >> 4;        // cell: batch row 0..15
    const int nn   = tid & 15;        // cell: col within chunk

    // ---- load this wave's weight slice into registers (held across all 512 steps) ----
    bf16x8 ufr[12], wfr[4];
    {
        const short* ub = Up + ((long)(unit * 4 + w) * 12) * 512 + lane * 8;
        #pragma unroll
        for (int kt = 0; kt < 12; ++kt) ufr[kt] = *(const bf16x8*)(ub + kt * 512);
        const short* wb = Wp + ((long)(unit * 4 + w) * 4) * 512 + lane * 8;
        #pragma unroll
        for (int kt = 0; kt < 4; ++kt) wfr[kt] = *(const bf16x8*)(wb + kt * 512);
    }
    for (int i = tid; i < NL * 128; i += 256) G_lds[i] = Gp[i];
    if (tid == 0) s_abort = 0;
    float c_reg = 0.f;
    __syncthreads();

    for (int t = 0; t < S_LEN; ++t) {
        const int par  = t & 1;        // h produced at step t lives in buf[par]
        const int ppar = par ^ 1;      // h produced at t-1

        // ================= U phase =================
        if (t == 0) {
            for (int i = tid; i < 16 * HXS; i += 256) hx_lds[i] = 0;
        } else {
            // wait: all layer-2 units of this group published h[t-1]
            if (tid == 0) {
                const unsigned fidx = ((unsigned)(t - 1) * 3 + 2) * 8 + grp;
                int guard = 0;
                while (!s_abort &&
                       __hip_atomic_load(&flags[fidx], __ATOMIC_ACQUIRE, __HIP_MEMORY_SCOPE_AGENT) < 8u) {
                    __builtin_amdgcn_s_sleep(2);
                    if (++guard > 4000000) s_abort = 1;
                }
            }
            __syncthreads();
            // read h[t-1] (all 3 layers, 16 rows, 128 cols) from LLC
            const unsigned* src = hexch + (unsigned)(ppar * 8 + grp) * (NL * 16 * 64);
            for (int i = tid; i < NL * 16 * 64; i += 256)
                hraw[i] = __hip_atomic_load(&src[i], __ATOMIC_RELAXED, __HIP_MEMORY_SCOPE_AGENT);
            __syncthreads();
            // per-(l,b) scalar gate: gh = sigm(h . G[l])
            #pragma unroll
            for (int i = 0; i < 12; ++i) {
                int p = w * 12 + i;          // 48 dots over 4 waves
                unsigned u = hraw[p * 64 + lane];
                float part = bf2f_lo(u) * G_lds[(p >> 4) * 128 + 2 * lane]
                           + bf2f_hi(u) * G_lds[(p >> 4) * 128 + 2 * lane + 1];
                #pragma unroll
                for (int m = 32; m >= 1; m >>= 1) part += __shfl_xor(part, m, 64);
                if (lane == 0) gh_lds[p] = sigm(part);
            }
            __syncthreads();
            // hx = gh * h  (bf16) into fragment-readable LDS
            for (int i = tid; i < NL * 16 * 64; i += 256) {
                int li = i >> 10, bi = (i >> 6) & 15, kw = i & 63;
                unsigned u = hraw[i];
                float g = gh_lds[li * 16 + bi];
                unsigned r = (unsigned)(unsigned short)f2bf(g * bf2f_lo(u))
                           | ((unsigned)(unsigned short)f2bf(g * bf2f_hi(u)) << 16);
                *(unsigned*)&hx_lds[bi * HXS + li * 128 + 2 * kw] = r;
            }
        }
        __syncthreads();   // hx ready

        f32x4 acc = (f32x4){0.f, 0.f, 0.f, 0.f};
        #pragma unroll
        for (int kt = 0; kt < 12; ++kt) {
            bf16x8 a = *(const bf16x8*)&hx_lds[lr * HXS + kt * 32 + lk * 8];
            acc = __builtin_amdgcn_mfma_f32_16x16x32_bf16(a, ufr[kt], acc, 0, 0, 0);
        }

        // ================= W phase =================
        if (l == 0) {
            const short* xp_t = xp + ((long)t * BATCH + b0) * 128;
            #pragma unroll
            for (int kt = 0; kt < 4; ++kt) {
                bf16x8 a = *(const bf16x8*)(xp_t + lr * 128 + kt * 32 + lk * 8);
                acc = __builtin_amdgcn_mfma_f32_16x16x32_bf16(a, wfr[kt], acc, 0, 0, 0);
            }
        } else {
            if (tid == 0) {
                const unsigned fidx = ((unsigned)t * 3 + (l - 1)) * 8 + grp;
                int guard = 0;
                while (!s_abort &&
                       __hip_atomic_load(&flags[fidx], __ATOMIC_ACQUIRE, __HIP_MEMORY_SCOPE_AGENT) < 8u) {
                    __builtin_amdgcn_s_sleep(2);
                    if (++guard > 4000000) s_abort = 1;
                }
            }
            __syncthreads();
            const unsigned* isrc = hexch + (unsigned)(par * 8 + grp) * (NL * 16 * 64) + (l - 1) * 16 * 64;
            for (int i = tid; i < 16 * 64; i += 256) {
                int bi = i >> 6, kw = i & 63;
                unsigned u = __hip_atomic_load(&isrc[i], __ATOMIC_RELAXED, __HIP_MEMORY_SCOPE_AGENT);
                *(unsigned*)&inp_lds[bi * INPS + 2 * kw] = u;
            }
            __syncthreads();
            #pragma unroll
            for (int kt = 0; kt < 4; ++kt) {
                bf16x8 a = *(const bf16x8*)&inp_lds[lr * INPS + kt * 32 + lk * 8];
                acc = __builtin_amdgcn_mfma_f32_16x16x32_bf16(a, wfr[kt], acc, 0, 0, 0);
            }
        }

        // ================= cell =================
        // D layout: col n = lane&15, row m = (lane>>4)*4 + r
        #pragma unroll
        for (int r = 0; r < 4; ++r)
            gates_lds[w * 272 + (lk * 4 + r) * 17 + lr] = acc[r];
        __syncthreads();

        float ig = sigm(gates_lds[0 * 272 + bb * 17 + nn]);
        float fg = sigm(gates_lds[1 * 272 + bb * 17 + nn]);
        float gg = tanh_fast(gates_lds[2 * 272 + bb * 17 + nn]);
        float og = sigm(gates_lds[3 * 272 + bb * 17 + nn]);
        float cn = fg * c_reg + ig * gg;
        c_reg = cn;
        float hy = og * tanh_fast(cn);
        hsl[bb * 16 + nn] = f2bf(hy);
        __syncthreads();

        // ================= publish =================
        if (tid < 128) {
            int row = tid >> 3, qq = tid & 7;
            unsigned v = *(const unsigned*)&hsl[row * 16 + qq * 2];
            unsigned* dst = hexch + (unsigned)(par * 8 + grp) * (NL * 16 * 64)
                          + (unsigned)(l * 16 + row) * 64 + c * 8 + qq;
            __hip_atomic_store(dst, v, __ATOMIC_RELAXED, __HIP_MEMORY_SCOPE_AGENT);
        }
        __threadfence();
        __syncthreads();
        if (tid == 0)
            __hip_atomic_fetch_add(&flags[((unsigned)t * 3 + l) * 8 + grp], 1u,
                                   __ATOMIC_RELEASE, __HIP_MEMORY_SCOPE_AGENT);

        if (t == S_LEN - 1) {
            long o = ((long)(l * BATCH + b0 + bb)) * NH + c * 16 + nn;
            out[o] = hy;
            out[(long)NL * BATCH * NH + o] = cn;
        }
    }
}

extern "C" void kernel_launch(void* const* d_in, const int* in_sizes, int n_in,
                              void* d_out, int out_size, void* d_ws, size_t ws_size,
                              hipStream_t stream) {
    const float* x     = (const float*)d_in[0];
    const float* lin_w = (const float*)d_in[1];
    const float* lin_b = (const float*)d_in[2];
    const float* W     = (const float*)d_in[3];
    const float* U     = (const float*)d_in[4];
    const float* G     = (const float*)d_in[5];
    float* out = (float*)d_out;

    short*    xp    = (short*)((char*)d_ws + XP_OFF);
    short*    Wp    = (short*)((char*)d_ws + WP_OFF);
    short*    Up    = (short*)((char*)d_ws + UP_OFF);
    unsigned* hexch = (unsigned*)((char*)d_ws + HX_OFF);
    unsigned* flags = (unsigned*)((char*)d_ws + FLAG_OFF);

    hipMemsetAsync(flags, 0, FLAG_SZ, stream);
    hipLaunchKernelGGL(xp_kernel,   dim3(8192), dim3(128), 0, stream, x, lin_w, lin_b, xp);
    hipLaunchKernelGGL(pack_kernel, dim3(384),  dim3(256), 0, stream, W, U, Wp, Up);
    hipLaunchKernelGGL(lstm_kernel, dim3(192),  dim3(256), 0, stream,
                       xp, Wp, Up, G, hexch, flags, out);
}

// Round 6
// 13932.280 us; speedup vs baseline: 2.0374x; 2.0374x over previous
//
#include <hip/hip_runtime.h>

#define S_LEN 512
#define BATCH 128
#define NH    128
#define NL    3

#define HXS  392   // hx row stride (shorts)
#define INPS 136   // inp row stride (shorts)

// workspace layout (bytes)
#define XP_OFF   0u
#define WP_OFF   16777216u              // 384 frags * 1KB
#define UP_OFF   (WP_OFF + 393216u)     // 1152 frags * 1KB
#define HX_OFF   (UP_OFF + 1179648u)    // 2 par * 8 grp * 3 l * 16*128 bf16 = 196608
#define FLAG_OFF (HX_OFF + 196608u)     // 512*3*8 u32 = 49152
#define FLAG_SZ  49152u

typedef float f32x4 __attribute__((ext_vector_type(4)));
typedef short bf16x8 __attribute__((ext_vector_type(8)));

__device__ __forceinline__ short f2bf(float f) {
    unsigned u = __builtin_bit_cast(unsigned, f);
    u = (u + 0x7FFFu + ((u >> 16) & 1u)) >> 16;
    return (short)u;
}
__device__ __forceinline__ float bf2f(short s) {
    unsigned u = ((unsigned)(unsigned short)s) << 16;
    return __builtin_bit_cast(float, u);
}
__device__ __forceinline__ float bf2f_lo(unsigned u) { return __builtin_bit_cast(float, u << 16); }
__device__ __forceinline__ float bf2f_hi(unsigned u) { return __builtin_bit_cast(float, u & 0xFFFF0000u); }
__device__ __forceinline__ float sigm(float x) { return 1.f / (1.f + __expf(-x)); }
__device__ __forceinline__ float tanh_fast(float x) { return 2.f / (1.f + __expf(-2.f * x)) - 1.f; }

// ---------------- K1: xp = x @ lin_w.T + lin_b  ->  bf16 [S*B][H] ----------------
__global__ __launch_bounds__(128) void xp_kernel(const float* __restrict__ x,
        const float* __restrict__ lin_w, const float* __restrict__ lin_b,
        short* __restrict__ xp) {
    __shared__ float xs[8 * 128];
    const int tid = threadIdx.x;
    const long r0 = (long)blockIdx.x * 8;
    for (int rr = 0; rr < 8; ++rr)
        xs[rr * 128 + tid] = x[(r0 + rr) * 128 + tid];
    __syncthreads();
    float acc[8];
    float bias = lin_b[tid];
    #pragma unroll
    for (int rr = 0; rr < 8; ++rr) acc[rr] = bias;
    const float* wrow = lin_w + (long)tid * 128;
    for (int k = 0; k < 128; ++k) {
        float wv = wrow[k];
        #pragma unroll
        for (int rr = 0; rr < 8; ++rr) acc[rr] += xs[rr * 128 + k] * wv;
    }
    for (int rr = 0; rr < 8; ++rr)
        xp[(r0 + rr) * 128 + tid] = f2bf(acc[rr]);
}

// ---------------- K2: pack W,U per (unit, gate-wave) fragment-linear ----------------
// unit = l*8 + c  (c = 16-col h-chunk). Wave g of a unit owns rows g*128 + c*16 + [0,16).
// Fragment: lane(lr=lane&15, lk=lane>>4), elem j -> row base+lr, col kt*32 + lk*8 + j.
// Wp frag id = (unit*4+g)*4 + kt    [384]
// Up frag id = (unit*4+g)*12 + kt   [1152]
__global__ __launch_bounds__(256) void pack_kernel(const float* __restrict__ W,
        const float* __restrict__ U, short* __restrict__ Wp, short* __restrict__ Up) {
    int id = blockIdx.x * 256 + threadIdx.x;     // 98304 = 1536 frags * 64 lanes
    int lane = id & 63;
    int fid = id >> 6;
    int lr = lane & 15, lk = lane >> 4;
    if (fid < 384) {
        int kt = fid & 3, g = (fid >> 2) & 3, unit = fid >> 4;
        int l = unit >> 3, c = unit & 7;
        int row = g * 128 + c * 16 + lr;
        const float* src = W + ((long)(l * 512 + row)) * 128 + kt * 32 + lk * 8;
        short* dst = Wp + (long)fid * 512 + lane * 8;
        #pragma unroll
        for (int j = 0; j < 8; ++j) dst[j] = f2bf(src[j]);
    } else {
        int f = fid - 384;
        int kt = f % 12, gu = f / 12;
        int g = gu & 3, unit = gu >> 2;
        int l = unit >> 3, c = unit & 7;
        int row = g * 128 + c * 16 + lr;
        const float* src = U + ((long)(l * 512 + row)) * 384 + kt * 32 + lk * 8;
        short* dst = Up + (long)f * 512 + lane * 8;
        #pragma unroll
        for (int j = 0; j < 8; ++j) dst[j] = f2bf(src[j]);
    }
}

// ---------------- main: 192 WGs (24 units x 8 batch groups), weights in VGPRs ----------------
__global__ __launch_bounds__(256, 1) void lstm_kernel(
    const short* __restrict__ xp, const short* __restrict__ Wp,
    const short* __restrict__ Up, const float* __restrict__ Gp,
    unsigned* __restrict__ hexch, unsigned* __restrict__ flags,
    float* __restrict__ out)
{
    __shared__ short hx_lds[16 * HXS];        // 12544 B
    __shared__ short inp_lds[16 * INPS];      //  4352 B
    __shared__ unsigned hraw[NL * 16 * 64];   // 12288 B (u32 view of h[3][16][128])
    __shared__ float gates_lds[4 * 16 * 17];  //  4352 B
    __shared__ float G_lds[NL * 128];         //  1536 B
    __shared__ float gh_lds[48];
    __shared__ short hsl[16 * 16];            //   512 B
    __shared__ int s_abort;

    const int tid  = threadIdx.x;
    const int lane = tid & 63;
    const int w    = tid >> 6;        // wave 0..3 = gate index (i,f,g,o)
    const int lr   = lane & 15;
    const int lk   = lane >> 4;
    const int grp  = blockIdx.x & 7;  // batch group (XCD-affine; perf only)
    const int unit = blockIdx.x >> 3; // 0..23
    const int l    = unit >> 3;       // owned layer
    const int c    = unit & 7;        // owned 16-col h-chunk
    const int b0   = grp * 16;
    const int bb   = tid >> 4;        // cell: batch row 0..15
    const int nn   = tid & 15;        // cell: col within chunk

    // ---- load this wave's weight slice into registers (held across all 512 steps) ----
    bf16x8 ufr[12], wfr[4];
    {
        const short* ub = Up + ((long)(unit * 4 + w) * 12) * 512 + lane * 8;
        #pragma unroll
        for (int kt = 0; kt < 12; ++kt) ufr[kt] = *(const bf16x8*)(ub + kt * 512);
        const short* wb = Wp + ((long)(unit * 4 + w) * 4) * 512 + lane * 8;
        #pragma unroll
        for (int kt = 0; kt < 4; ++kt) wfr[kt] = *(const bf16x8*)(wb + kt * 512);
    }
    for (int i = tid; i < NL * 128; i += 256) G_lds[i] = Gp[i];
    if (tid == 0) s_abort = 0;
    float c_reg = 0.f;
    __syncthreads();

    for (int t = 0; t < S_LEN; ++t) {
        const int par  = t & 1;        // h produced at step t lives in buf[par]
        const int ppar = par ^ 1;      // h produced at t-1

        // ================= U phase =================
        if (t == 0) {
            for (int i = tid; i < 16 * HXS; i += 256) hx_lds[i] = 0;
        } else {
            // wait: all layer-2 units of this group published h[t-1]
            if (tid == 0) {
                const unsigned fidx = ((unsigned)(t - 1) * 3 + 2) * 8 + grp;
                int guard = 0;
                while (!s_abort &&
                       __hip_atomic_load(&flags[fidx], __ATOMIC_ACQUIRE, __HIP_MEMORY_SCOPE_AGENT) < 8u) {
                    __builtin_amdgcn_s_sleep(2);
                    if (++guard > 4000000) s_abort = 1;
                }
            }
            __syncthreads();
            // read h[t-1] (all 3 layers, 16 rows, 128 cols) from LLC
            const unsigned* src = hexch + (unsigned)(ppar * 8 + grp) * (NL * 16 * 64);
            for (int i = tid; i < NL * 16 * 64; i += 256)
                hraw[i] = __hip_atomic_load(&src[i], __ATOMIC_RELAXED, __HIP_MEMORY_SCOPE_AGENT);
            __syncthreads();
            // per-(l,b) scalar gate: gh = sigm(h . G[l])
            #pragma unroll
            for (int i = 0; i < 12; ++i) {
                int p = w * 12 + i;          // 48 dots over 4 waves
                unsigned u = hraw[p * 64 + lane];
                float part = bf2f_lo(u) * G_lds[(p >> 4) * 128 + 2 * lane]
                           + bf2f_hi(u) * G_lds[(p >> 4) * 128 + 2 * lane + 1];
                #pragma unroll
                for (int m = 32; m >= 1; m >>= 1) part += __shfl_xor(part, m, 64);
                if (lane == 0) gh_lds[p] = sigm(part);
            }
            __syncthreads();
            // hx = gh * h  (bf16) into fragment-readable LDS
            for (int i = tid; i < NL * 16 * 64; i += 256) {
                int li = i >> 10, bi = (i >> 6) & 15, kw = i & 63;
                unsigned u = hraw[i];
                float g = gh_lds[li * 16 + bi];
                unsigned r = (unsigned)(unsigned short)f2bf(g * bf2f_lo(u))
                           | ((unsigned)(unsigned short)f2bf(g * bf2f_hi(u)) << 16);
                *(unsigned*)&hx_lds[bi * HXS + li * 128 + 2 * kw] = r;
            }
        }
        __syncthreads();   // hx ready

        f32x4 acc = (f32x4){0.f, 0.f, 0.f, 0.f};
        #pragma unroll
        for (int kt = 0; kt < 12; ++kt) {
            bf16x8 a = *(const bf16x8*)&hx_lds[lr * HXS + kt * 32 + lk * 8];
            acc = __builtin_amdgcn_mfma_f32_16x16x32_bf16(a, ufr[kt], acc, 0, 0, 0);
        }

        // ================= W phase =================
        if (l == 0) {
            const short* xp_t = xp + ((long)t * BATCH + b0) * 128;
            #pragma unroll
            for (int kt = 0; kt < 4; ++kt) {
                bf16x8 a = *(const bf16x8*)(xp_t + lr * 128 + kt * 32 + lk * 8);
                acc = __builtin_amdgcn_mfma_f32_16x16x32_bf16(a, wfr[kt], acc, 0, 0, 0);
            }
        } else {
            if (tid == 0) {
                const unsigned fidx = ((unsigned)t * 3 + (l - 1)) * 8 + grp;
                int guard = 0;
                while (!s_abort &&
                       __hip_atomic_load(&flags[fidx], __ATOMIC_ACQUIRE, __HIP_MEMORY_SCOPE_AGENT) < 8u) {
                    __builtin_amdgcn_s_sleep(2);
                    if (++guard > 4000000) s_abort = 1;
                }
            }
            __syncthreads();
            const unsigned* isrc = hexch + (unsigned)(par * 8 + grp) * (NL * 16 * 64) + (l - 1) * 16 * 64;
            for (int i = tid; i < 16 * 64; i += 256) {
                int bi = i >> 6, kw = i & 63;
                unsigned u = __hip_atomic_load(&isrc[i], __ATOMIC_RELAXED, __HIP_MEMORY_SCOPE_AGENT);
                *(unsigned*)&inp_lds[bi * INPS + 2 * kw] = u;
            }
            __syncthreads();
            #pragma unroll
            for (int kt = 0; kt < 4; ++kt) {
                bf16x8 a = *(const bf16x8*)&inp_lds[lr * INPS + kt * 32 + lk * 8];
                acc = __builtin_amdgcn_mfma_f32_16x16x32_bf16(a, wfr[kt], acc, 0, 0, 0);
            }
        }

        // ================= cell =================
        // D layout: col n = lane&15, row m = (lane>>4)*4 + r
        #pragma unroll
        for (int r = 0; r < 4; ++r)
            gates_lds[w * 272 + (lk * 4 + r) * 17 + lr] = acc[r];
        __syncthreads();

        float ig = sigm(gates_lds[0 * 272 + bb * 17 + nn]);
        float fg = sigm(gates_lds[1 * 272 + bb * 17 + nn]);
        float gg = tanh_fast(gates_lds[2 * 272 + bb * 17 + nn]);
        float og = sigm(gates_lds[3 * 272 + bb * 17 + nn]);
        float cn = fg * c_reg + ig * gg;
        c_reg = cn;
        float hy = og * tanh_fast(cn);
        hsl[bb * 16 + nn] = f2bf(hy);
        __syncthreads();

        // ================= publish (release fetch_add orders the stores) =================
        if (tid < 128) {
            int row = tid >> 3, qq = tid & 7;
            unsigned v = *(const unsigned*)&hsl[row * 16 + qq * 2];
            unsigned* dst = hexch + (unsigned)(par * 8 + grp) * (NL * 16 * 64)
                          + (unsigned)(l * 16 + row) * 64 + c * 8 + qq;
            __hip_atomic_store(dst, v, __ATOMIC_RELAXED, __HIP_MEMORY_SCOPE_AGENT);
        }
        __syncthreads();
        if (tid == 0)
            __hip_atomic_fetch_add(&flags[((unsigned)t * 3 + l) * 8 + grp], 1u,
                                   __ATOMIC_RELEASE, __HIP_MEMORY_SCOPE_AGENT);

        if (t == S_LEN - 1) {
            long o = ((long)(l * BATCH + b0 + bb)) * NH + c * 16 + nn;
            out[o] = hy;
            out[(long)NL * BATCH * NH + o] = cn;
        }
    }
}

extern "C" void kernel_launch(void* const* d_in, const int* in_sizes, int n_in,
                              void* d_out, int out_size, void* d_ws, size_t ws_size,
                              hipStream_t stream) {
    const float* x     = (const float*)d_in[0];
    const float* lin_w = (const float*)d_in[1];
    const float* lin_b = (const float*)d_in[2];
    const float* W     = (const float*)d_in[3];
    const float* U     = (const float*)d_in[4];
    const float* G     = (const float*)d_in[5];
    float* out = (float*)d_out;

    short*    xp    = (short*)((char*)d_ws + XP_OFF);
    short*    Wp    = (short*)((char*)d_ws + WP_OFF);
    short*    Up    = (short*)((char*)d_ws + UP_OFF);
    unsigned* hexch = (unsigned*)((char*)d_ws + HX_OFF);
    unsigned* flags = (unsigned*)((char*)d_ws + FLAG_OFF);

    hipMemsetAsync(flags, 0, FLAG_SZ, stream);
    hipLaunchKernelGGL(xp_kernel,   dim3(8192), dim3(128), 0, stream, x, lin_w, lin_b, xp);
    hipLaunchKernelGGL(pack_kernel, dim3(384),  dim3(256), 0, stream, W, U, Wp, Up);
    hipLaunchKernelGGL(lstm_kernel, dim3(192),  dim3(256), 0, stream,
                       xp, Wp, Up, G, hexch, flags, out);
}

// Round 7
// 6368.937 us; speedup vs baseline: 4.4569x; 2.1875x over previous
//
#include <hip/hip_runtime.h>

#define S_LEN 512
#define BATCH 128
#define NH    128
#define NL    3

#define HXS  392   // hx row stride (shorts)
#define INPS 136   // inp row stride (shorts)

// workspace layout (bytes)
#define XP_OFF   0u
#define WP_OFF   16777216u              // 384 frags * 1KB
#define UP_OFF   (WP_OFF + 393216u)     // 1152 frags * 1KB
#define HX_OFF   (UP_OFF + 1179648u)    // 2 par * 8 grp * 3 l * 16*128 bf16 = 196608
#define FLAG_OFF (HX_OFF + 196608u)     // 512*3*8 u32 = 49152
#define FLAG_SZ  49152u

typedef float f32x4 __attribute__((ext_vector_type(4)));
typedef short bf16x8 __attribute__((ext_vector_type(8)));
typedef unsigned long long u64;

__device__ __forceinline__ short f2bf(float f) {
    unsigned u = __builtin_bit_cast(unsigned, f);
    u = (u + 0x7FFFu + ((u >> 16) & 1u)) >> 16;
    return (short)u;
}
__device__ __forceinline__ float bf2f(short s) {
    unsigned u = ((unsigned)(unsigned short)s) << 16;
    return __builtin_bit_cast(float, u);
}
__device__ __forceinline__ float bf2f_lo(unsigned u) { return __builtin_bit_cast(float, u << 16); }
__device__ __forceinline__ float bf2f_hi(unsigned u) { return __builtin_bit_cast(float, u & 0xFFFF0000u); }
__device__ __forceinline__ float sigm(float x) { return 1.f / (1.f + __expf(-x)); }
__device__ __forceinline__ float tanh_fast(float x) { return 2.f / (1.f + __expf(-2.f * x)) - 1.f; }

// ---------------- K1: xp = x @ lin_w.T + lin_b  ->  bf16 [S*B][H] ----------------
__global__ __launch_bounds__(128) void xp_kernel(const float* __restrict__ x,
        const float* __restrict__ lin_w, const float* __restrict__ lin_b,
        short* __restrict__ xp) {
    __shared__ float xs[8 * 128];
    const int tid = threadIdx.x;
    const long r0 = (long)blockIdx.x * 8;
    for (int rr = 0; rr < 8; ++rr)
        xs[rr * 128 + tid] = x[(r0 + rr) * 128 + tid];
    __syncthreads();
    float acc[8];
    float bias = lin_b[tid];
    #pragma unroll
    for (int rr = 0; rr < 8; ++rr) acc[rr] = bias;
    const float* wrow = lin_w + (long)tid * 128;
    for (int k = 0; k < 128; ++k) {
        float wv = wrow[k];
        #pragma unroll
        for (int rr = 0; rr < 8; ++rr) acc[rr] += xs[rr * 128 + k] * wv;
    }
    for (int rr = 0; rr < 8; ++rr)
        xp[(r0 + rr) * 128 + tid] = f2bf(acc[rr]);
}

// ---------------- K2: pack W,U per (unit, gate-wave) fragment-linear ----------------
// unit = l*8 + c  (c = 16-col h-chunk). Wave g of a unit owns rows g*128 + c*16 + [0,16).
// Fragment: lane(lr=lane&15, lk=lane>>4), elem j -> row base+lr, col kt*32 + lk*8 + j.
// Wp frag id = (unit*4+g)*4 + kt    [384]
// Up frag id = (unit*4+g)*12 + kt   [1152]
__global__ __launch_bounds__(256) void pack_kernel(const float* __restrict__ W,
        const float* __restrict__ U, short* __restrict__ Wp, short* __restrict__ Up) {
    int id = blockIdx.x * 256 + threadIdx.x;     // 98304 = 1536 frags * 64 lanes
    int lane = id & 63;
    int fid = id >> 6;
    int lr = lane & 15, lk = lane >> 4;
    if (fid < 384) {
        int kt = fid & 3, g = (fid >> 2) & 3, unit = fid >> 4;
        int l = unit >> 3, c = unit & 7;
        int row = g * 128 + c * 16 + lr;
        const float* src = W + ((long)(l * 512 + row)) * 128 + kt * 32 + lk * 8;
        short* dst = Wp + (long)fid * 512 + lane * 8;
        #pragma unroll
        for (int j = 0; j < 8; ++j) dst[j] = f2bf(src[j]);
    } else {
        int f = fid - 384;
        int kt = f % 12, gu = f / 12;
        int g = gu & 3, unit = gu >> 2;
        int l = unit >> 3, c = unit & 7;
        int row = g * 128 + c * 16 + lr;
        const float* src = U + ((long)(l * 512 + row)) * 384 + kt * 32 + lk * 8;
        short* dst = Up + (long)f * 512 + lane * 8;
        #pragma unroll
        for (int j = 0; j < 8; ++j) dst[j] = f2bf(src[j]);
    }
}

// ---------------- main: 192 WGs (24 units x 8 batch groups), weights in VGPRs ----------------
__global__ __launch_bounds__(256, 1) void lstm_kernel(
    const short* __restrict__ xp, const short* __restrict__ Wp,
    const short* __restrict__ Up, const float* __restrict__ Gp,
    unsigned* __restrict__ hexch, unsigned* __restrict__ flags,
    float* __restrict__ out)
{
    __shared__ short hx_lds[16 * HXS];        // 12544 B
    __shared__ short inp_lds[16 * INPS];      //  4352 B
    __shared__ unsigned hraw[NL * 16 * 64];   // 12288 B (u32 view of h[3][16][128])
    __shared__ float gates_lds[4 * 16 * 17];  //  4352 B
    __shared__ float G_lds[NL * 128];         //  1536 B
    __shared__ float gh_lds[48];
    __shared__ short hsl[16 * 16];            //   512 B
    __shared__ int s_abort;

    const int tid  = threadIdx.x;
    const int lane = tid & 63;
    const int w    = tid >> 6;        // wave 0..3 = gate index (i,f,g,o)
    const int lr   = lane & 15;
    const int lk   = lane >> 4;
    const int grp  = blockIdx.x & 7;  // batch group (XCD-affine; perf only)
    const int unit = blockIdx.x >> 3; // 0..23
    const int l    = unit >> 3;       // owned layer
    const int c    = unit & 7;        // owned 16-col h-chunk
    const int b0   = grp * 16;
    const int bb   = tid >> 4;        // cell: batch row 0..15
    const int nn   = tid & 15;        // cell: col within chunk

    // ---- load this wave's weight slice into registers, pinned via opaque asm ----
    bf16x8 ufr[12], wfr[4];
    {
        const short* ub = Up + ((long)(unit * 4 + w) * 12) * 512 + lane * 8;
        #pragma unroll
        for (int kt = 0; kt < 12; ++kt) ufr[kt] = *(const bf16x8*)(ub + kt * 512);
        const short* wb = Wp + ((long)(unit * 4 + w) * 4) * 512 + lane * 8;
        #pragma unroll
        for (int kt = 0; kt < 4; ++kt) wfr[kt] = *(const bf16x8*)(wb + kt * 512);
    }
    // opaque touch: values become asm-defined -> cannot be rematerialized each step
    #pragma unroll
    for (int kt = 0; kt < 12; ++kt) asm volatile("" : "+v"(ufr[kt]));
    #pragma unroll
    for (int kt = 0; kt < 4; ++kt)  asm volatile("" : "+v"(wfr[kt]));

    for (int i = tid; i < NL * 128; i += 256) G_lds[i] = Gp[i];
    if (tid == 0) s_abort = 0;
    float c_reg = 0.f;
    __syncthreads();

    for (int t = 0; t < S_LEN; ++t) {
        const int par  = t & 1;        // h produced at step t lives in buf[par]
        const int ppar = par ^ 1;      // h produced at t-1

        // ================= U phase =================
        if (t == 0) {
            for (int i = tid; i < 16 * HXS; i += 256) hx_lds[i] = 0;
        } else {
            // wait: all layer-2 units of this group published h[t-1]  (RELAXED poll: no L2 inv)
            if (tid == 0) {
                const unsigned fidx = ((unsigned)(t - 1) * 3 + 2) * 8 + grp;
                int guard = 0;
                while (!s_abort &&
                       __hip_atomic_load(&flags[fidx], __ATOMIC_RELAXED, __HIP_MEMORY_SCOPE_AGENT) < 8u) {
                    __builtin_amdgcn_s_sleep(2);
                    if (++guard > 4000000) s_abort = 1;
                }
            }
            __syncthreads();
            // read h[t-1] (3 layers x 16 rows x 128 cols) from LLC, u64-wide
            const u64* src64 = (const u64*)(hexch + (unsigned)(ppar * 8 + grp) * (NL * 16 * 64));
            for (int i = tid; i < NL * 16 * 32; i += 256)
                ((u64*)hraw)[i] = __hip_atomic_load(&src64[i], __ATOMIC_RELAXED, __HIP_MEMORY_SCOPE_AGENT);
            __syncthreads();
            // per-(l,b) scalar gate: gh = sigm(h . G[l])
            #pragma unroll
            for (int i = 0; i < 12; ++i) {
                int p = w * 12 + i;          // 48 dots over 4 waves
                unsigned u = hraw[p * 64 + lane];
                float part = bf2f_lo(u) * G_lds[(p >> 4) * 128 + 2 * lane]
                           + bf2f_hi(u) * G_lds[(p >> 4) * 128 + 2 * lane + 1];
                #pragma unroll
                for (int m = 32; m >= 1; m >>= 1) part += __shfl_xor(part, m, 64);
                if (lane == 0) gh_lds[p] = sigm(part);
            }
            __syncthreads();
            // hx = gh * h  (bf16) into fragment-readable LDS
            for (int i = tid; i < NL * 16 * 64; i += 256) {
                int li = i >> 10, bi = (i >> 6) & 15, kw = i & 63;
                unsigned u = hraw[i];
                float g = gh_lds[li * 16 + bi];
                unsigned r = (unsigned)(unsigned short)f2bf(g * bf2f_lo(u))
                           | ((unsigned)(unsigned short)f2bf(g * bf2f_hi(u)) << 16);
                *(unsigned*)&hx_lds[bi * HXS + li * 128 + 2 * kw] = r;
            }
        }
        __syncthreads();   // hx ready

        f32x4 acc = (f32x4){0.f, 0.f, 0.f, 0.f};
        #pragma unroll
        for (int kt = 0; kt < 12; ++kt) {
            bf16x8 a = *(const bf16x8*)&hx_lds[lr * HXS + kt * 32 + lk * 8];
            acc = __builtin_amdgcn_mfma_f32_16x16x32_bf16(a, ufr[kt], acc, 0, 0, 0);
        }

        // ================= W phase =================
        if (l == 0) {
            const short* xp_t = xp + ((long)t * BATCH + b0) * 128;
            #pragma unroll
            for (int kt = 0; kt < 4; ++kt) {
                bf16x8 a = *(const bf16x8*)(xp_t + lr * 128 + kt * 32 + lk * 8);
                acc = __builtin_amdgcn_mfma_f32_16x16x32_bf16(a, wfr[kt], acc, 0, 0, 0);
            }
        } else {
            if (tid == 0) {
                const unsigned fidx = ((unsigned)t * 3 + (l - 1)) * 8 + grp;
                int guard = 0;
                while (!s_abort &&
                       __hip_atomic_load(&flags[fidx], __ATOMIC_RELAXED, __HIP_MEMORY_SCOPE_AGENT) < 8u) {
                    __builtin_amdgcn_s_sleep(2);
                    if (++guard > 4000000) s_abort = 1;
                }
            }
            __syncthreads();
            const u64* isrc64 = (const u64*)(hexch + (unsigned)(par * 8 + grp) * (NL * 16 * 64)
                                             + (l - 1) * 16 * 64);
            for (int i = tid; i < 16 * 32; i += 256) {   // 512 u64
                int bi = i >> 5, kq = i & 31;
                u64 u = __hip_atomic_load(&isrc64[i], __ATOMIC_RELAXED, __HIP_MEMORY_SCOPE_AGENT);
                *(u64*)&inp_lds[bi * INPS + 4 * kq] = u;
            }
            __syncthreads();
            #pragma unroll
            for (int kt = 0; kt < 4; ++kt) {
                bf16x8 a = *(const bf16x8*)&inp_lds[lr * INPS + kt * 32 + lk * 8];
                acc = __builtin_amdgcn_mfma_f32_16x16x32_bf16(a, wfr[kt], acc, 0, 0, 0);
            }
        }

        // ================= cell =================
        // D layout: col n = lane&15, row m = (lane>>4)*4 + r
        #pragma unroll
        for (int r = 0; r < 4; ++r)
            gates_lds[w * 272 + (lk * 4 + r) * 17 + lr] = acc[r];
        __syncthreads();

        float ig = sigm(gates_lds[0 * 272 + bb * 17 + nn]);
        float fg = sigm(gates_lds[1 * 272 + bb * 17 + nn]);
        float gg = tanh_fast(gates_lds[2 * 272 + bb * 17 + nn]);
        float og = sigm(gates_lds[3 * 272 + bb * 17 + nn]);
        float cn = fg * c_reg + ig * gg;
        c_reg = cn;
        float hy = og * tanh_fast(cn);
        hsl[bb * 16 + nn] = f2bf(hy);
        __syncthreads();

        // ================= publish: relaxed stores -> vmcnt(0) -> relaxed flag add =================
        if (tid < 64) {
            int row = tid >> 2, q = tid & 3;
            u64 v = ((const u64*)hsl)[tid];
            u64* dst = (u64*)(hexch + (unsigned)(par * 8 + grp) * (NL * 16 * 64)
                              + (unsigned)(l * 16 + row) * 64 + c * 8) + q;
            __hip_atomic_store(dst, v, __ATOMIC_RELAXED, __HIP_MEMORY_SCOPE_AGENT);
        }
        asm volatile("s_waitcnt vmcnt(0)" ::: "memory");   // data acks reach LLC before flag
        __syncthreads();
        if (tid == 0)
            __hip_atomic_fetch_add(&flags[((unsigned)t * 3 + l) * 8 + grp], 1u,
                                   __ATOMIC_RELAXED, __HIP_MEMORY_SCOPE_AGENT);

        if (t == S_LEN - 1) {
            long o = ((long)(l * BATCH + b0 + bb)) * NH + c * 16 + nn;
            out[o] = hy;
            out[(long)NL * BATCH * NH + o] = cn;
        }
    }
}

extern "C" void kernel_launch(void* const* d_in, const int* in_sizes, int n_in,
                              void* d_out, int out_size, void* d_ws, size_t ws_size,
                              hipStream_t stream) {
    const float* x     = (const float*)d_in[0];
    const float* lin_w = (const float*)d_in[1];
    const float* lin_b = (const float*)d_in[2];
    const float* W     = (const float*)d_in[3];
    const float* U     = (const float*)d_in[4];
    const float* G     = (const float*)d_in[5];
    float* out = (float*)d_out;

    short*    xp    = (short*)((char*)d_ws + XP_OFF);
    short*    Wp    = (short*)((char*)d_ws + WP_OFF);
    short*    Up    = (short*)((char*)d_ws + UP_OFF);
    unsigned* hexch = (unsigned*)((char*)d_ws + HX_OFF);
    unsigned* flags = (unsigned*)((char*)d_ws + FLAG_OFF);

    hipMemsetAsync(flags, 0, FLAG_SZ, stream);
    hipLaunchKernelGGL(xp_kernel,   dim3(8192), dim3(128), 0, stream, x, lin_w, lin_b, xp);
    hipLaunchKernelGGL(pack_kernel, dim3(384),  dim3(256), 0, stream, W, U, Wp, Up);
    hipLaunchKernelGGL(lstm_kernel, dim3(192),  dim3(256), 0, stream,
                       xp, Wp, Up, G, hexch, flags, out);
}

// Round 8
// 3900.809 us; speedup vs baseline: 7.2769x; 1.6327x over previous
//
#include <hip/hip_runtime.h>

#define S_LEN 512
#define BATCH 128
#define NH    128
#define NL    3

#define HXS  392   // hx row stride (shorts)
#define INPS 136   // inp row stride (shorts)

// workspace layout (bytes)
#define XP_OFF   0u
#define WP_OFF   16777216u              // 384 frags * 1KB
#define UP_OFF   (WP_OFF + 393216u)     // 1152 frags * 1KB
#define HX_OFF   (UP_OFF + 1179648u)    // 2 par * 8 grp * 3 l * 16*128 bf16 = 196608
#define FLAG_OFF (HX_OFF + 196608u)     // 512*3*8 u32 = 49152
#define FLAG_SZ  49152u

typedef float f32x4 __attribute__((ext_vector_type(4)));
typedef short bf16x8 __attribute__((ext_vector_type(8)));
typedef unsigned long long u64;

__device__ __forceinline__ short f2bf(float f) {
    unsigned u = __builtin_bit_cast(unsigned, f);
    u = (u + 0x7FFFu + ((u >> 16) & 1u)) >> 16;
    return (short)u;
}
__device__ __forceinline__ float bf2f_lo(unsigned u) { return __builtin_bit_cast(float, u << 16); }
__device__ __forceinline__ float bf2f_hi(unsigned u) { return __builtin_bit_cast(float, u & 0xFFFF0000u); }
__device__ __forceinline__ float sigm(float x) { return 1.f / (1.f + __expf(-x)); }
__device__ __forceinline__ float tanh_fast(float x) { return 2.f / (1.f + __expf(-2.f * x)) - 1.f; }

// ---------------- K1: xp = x @ lin_w.T + lin_b  ->  bf16 [S*B][H] ----------------
__global__ __launch_bounds__(128) void xp_kernel(const float* __restrict__ x,
        const float* __restrict__ lin_w, const float* __restrict__ lin_b,
        short* __restrict__ xp) {
    __shared__ float xs[8 * 128];
    const int tid = threadIdx.x;
    const long r0 = (long)blockIdx.x * 8;
    for (int rr = 0; rr < 8; ++rr)
        xs[rr * 128 + tid] = x[(r0 + rr) * 128 + tid];
    __syncthreads();
    float acc[8];
    float bias = lin_b[tid];
    #pragma unroll
    for (int rr = 0; rr < 8; ++rr) acc[rr] = bias;
    const float* wrow = lin_w + (long)tid * 128;
    for (int k = 0; k < 128; ++k) {
        float wv = wrow[k];
        #pragma unroll
        for (int rr = 0; rr < 8; ++rr) acc[rr] += xs[rr * 128 + k] * wv;
    }
    for (int rr = 0; rr < 8; ++rr)
        xp[(r0 + rr) * 128 + tid] = f2bf(acc[rr]);
}

// ---------------- K2: pack W,U per (unit, gate-wave) fragment-linear ----------------
// unit = l*8 + c. Wave g of a unit owns rows g*128 + c*16 + [0,16).
// Fragment: lane(lr=lane&15, lk=lane>>4), elem j -> row base+lr, col kt*32 + lk*8 + j.
// Wp frag id = (unit*4+g)*4 + kt    [384];  Up frag id = (unit*4+g)*12 + kt   [1152]
__global__ __launch_bounds__(256) void pack_kernel(const float* __restrict__ W,
        const float* __restrict__ U, short* __restrict__ Wp, short* __restrict__ Up) {
    int id = blockIdx.x * 256 + threadIdx.x;     // 98304 = 1536 frags * 64 lanes
    int lane = id & 63;
    int fid = id >> 6;
    int lr = lane & 15, lk = lane >> 4;
    if (fid < 384) {
        int kt = fid & 3, g = (fid >> 2) & 3, unit = fid >> 4;
        int l = unit >> 3, c = unit & 7;
        int row = g * 128 + c * 16 + lr;
        const float* src = W + ((long)(l * 512 + row)) * 128 + kt * 32 + lk * 8;
        short* dst = Wp + (long)fid * 512 + lane * 8;
        #pragma unroll
        for (int j = 0; j < 8; ++j) dst[j] = f2bf(src[j]);
    } else {
        int f = fid - 384;
        int kt = f % 12, gu = f / 12;
        int g = gu & 3, unit = gu >> 2;
        int l = unit >> 3, c = unit & 7;
        int row = g * 128 + c * 16 + lr;
        const float* src = U + ((long)(l * 512 + row)) * 384 + kt * 32 + lk * 8;
        short* dst = Up + (long)f * 512 + lane * 8;
        #pragma unroll
        for (int j = 0; j < 8; ++j) dst[j] = f2bf(src[j]);
    }
}

// ---------------- main: 192 WGs (24 units x 8 batch groups), weights in VGPRs ----------------
__global__ __launch_bounds__(256, 1) void lstm_kernel(
    const short* __restrict__ xp, const short* __restrict__ Wp,
    const short* __restrict__ Up, const float* __restrict__ Gp,
    unsigned* __restrict__ hexch, unsigned* __restrict__ flags,
    float* __restrict__ out)
{
    __shared__ short hx_lds[16 * HXS];        // 12544 B
    __shared__ short inp_lds[16 * INPS];      //  4352 B
    __shared__ float gates_lds[4 * 16 * 17];  //  4352 B
    __shared__ float G_lds[NL * 128];         //  1536 B
    __shared__ short hsl[16 * 16];            //   512 B
    __shared__ int s_abort;

    const int tid  = threadIdx.x;
    const int lane = tid & 63;
    const int w    = tid >> 6;        // wave 0..3 = gate index (i,f,g,o)
    const int lr   = lane & 15;
    const int lk   = lane >> 4;
    const int grp  = blockIdx.x & 7;  // batch group
    const int unit = blockIdx.x >> 3; // 0..23
    const int l    = unit >> 3;       // owned layer
    const int c    = unit & 7;        // owned 16-col h-chunk
    const int b0   = grp * 16;
    const int bb   = tid >> 4;        // cell: batch row 0..15
    const int nn   = tid & 15;        // cell: col within chunk

    u64* hexch64 = (u64*)hexch;

    // ---- load this wave's weight slice into registers, pinned via opaque asm ----
    bf16x8 ufr[12], wfr[4];
    {
        const short* ub = Up + ((long)(unit * 4 + w) * 12) * 512 + lane * 8;
        #pragma unroll
        for (int kt = 0; kt < 12; ++kt) ufr[kt] = *(const bf16x8*)(ub + kt * 512);
        const short* wb = Wp + ((long)(unit * 4 + w) * 4) * 512 + lane * 8;
        #pragma unroll
        for (int kt = 0; kt < 4; ++kt) wfr[kt] = *(const bf16x8*)(wb + kt * 512);
    }
    #pragma unroll
    for (int kt = 0; kt < 12; ++kt) asm volatile("" : "+v"(ufr[kt]));
    #pragma unroll
    for (int kt = 0; kt < 4; ++kt)  asm volatile("" : "+v"(wfr[kt]));

    for (int i = tid; i < NL * 128; i += 256) G_lds[i] = Gp[i];
    if (tid == 0) s_abort = 0;
    float c_reg = 0.f;
    __syncthreads();

    for (int t = 0; t < S_LEN; ++t) {
        const int par  = t & 1;
        const int ppar = par ^ 1;

        // ---- earliest possible: l0 units issue xp A-frag loads (overlap with polls) ----
        bf16x8 xa[4];
        if (l == 0) {
            const short* xp_t = xp + ((long)t * BATCH + b0) * 128;
            #pragma unroll
            for (int kt = 0; kt < 4; ++kt)
                xa[kt] = *(const bf16x8*)(xp_t + lr * 128 + kt * 32 + lk * 8);
        }

        // ================= U phase: per-layer sliced (wave ll owns layer ll) =================
        if (t == 0) {
            for (int i = tid; i < 16 * HXS; i += 256) hx_lds[i] = 0;
        } else if (w < 3) {
            // poll flag(t-1, layer w): for w<2 it is long since set (1 load)
            {
                const unsigned fidx = ((unsigned)(t - 1) * 3 + w) * 8 + grp;
                int g = 0;
                while (__hip_atomic_load(&flags[fidx], __ATOMIC_RELAXED, __HIP_MEMORY_SCOPE_AGENT) < 8u) {
                    if (*(volatile int*)&s_abort) break;
                    if (++g > 300000) { *(volatile int*)&s_abort = 1; break; }
                }
            }
            // read own 64B of h[layer w] straight into registers
            const int p = lane >> 2, sub = lane & 3;   // pair (b=p), 32-col segment
            const u64* src64 = hexch64 + (unsigned)(ppar * 8 + grp) * 1536
                             + (unsigned)(w * 16 + p) * 32 + sub * 8;
            u64 hv[8];
            #pragma unroll
            for (int k = 0; k < 8; ++k)
                hv[k] = __hip_atomic_load(&src64[k], __ATOMIC_RELAXED, __HIP_MEMORY_SCOPE_AGENT);
            // quad-split dot: gh = sigm(h[p,:] . G[w])
            const float* gbase = &G_lds[w * 128 + sub * 32];
            float s = 0.f;
            #pragma unroll
            for (int k = 0; k < 8; ++k) {
                unsigned lo = (unsigned)hv[k], hi = (unsigned)(hv[k] >> 32);
                s += bf2f_lo(lo) * gbase[4 * k + 0];
                s += bf2f_hi(lo) * gbase[4 * k + 1];
                s += bf2f_lo(hi) * gbase[4 * k + 2];
                s += bf2f_hi(hi) * gbase[4 * k + 3];
            }
            s += __shfl_xor(s, 1, 64);
            s += __shfl_xor(s, 2, 64);
            float gh = sigm(s);
            // hx slice: gh * h -> LDS (64B per lane, contiguous)
            #pragma unroll
            for (int k = 0; k < 8; ++k) {
                unsigned lo = (unsigned)hv[k], hi = (unsigned)(hv[k] >> 32);
                unsigned r0 = (unsigned)(unsigned short)f2bf(gh * bf2f_lo(lo))
                            | ((unsigned)(unsigned short)f2bf(gh * bf2f_hi(lo)) << 16);
                unsigned r1 = (unsigned)(unsigned short)f2bf(gh * bf2f_lo(hi))
                            | ((unsigned)(unsigned short)f2bf(gh * bf2f_hi(hi)) << 16);
                *(u64*)&hx_lds[p * HXS + w * 128 + sub * 32 + 4 * k] =
                    ((u64)r1 << 32) | (u64)r0;
            }
        }
        __syncthreads();   // hx ready

        f32x4 acc = (f32x4){0.f, 0.f, 0.f, 0.f};
        #pragma unroll
        for (int kt = 0; kt < 12; ++kt) {
            bf16x8 a = *(const bf16x8*)&hx_lds[lr * HXS + kt * 32 + lk * 8];
            acc = __builtin_amdgcn_mfma_f32_16x16x32_bf16(a, ufr[kt], acc, 0, 0, 0);
        }

        // ================= W phase =================
        if (l == 0) {
            #pragma unroll
            for (int kt = 0; kt < 4; ++kt)
                acc = __builtin_amdgcn_mfma_f32_16x16x32_bf16(xa[kt], wfr[kt], acc, 0, 0, 0);
        } else {
            {
                const unsigned fidx = ((unsigned)t * 3 + (l - 1)) * 8 + grp;
                int g = 0;
                while (__hip_atomic_load(&flags[fidx], __ATOMIC_RELAXED, __HIP_MEMORY_SCOPE_AGENT) < 8u) {
                    if (*(volatile int*)&s_abort) break;
                    if (++g > 300000) { *(volatile int*)&s_abort = 1; break; }
                }
            }
            // each wave that exits the poll loads its share immediately (data valid once flag==8)
            const u64* isrc64 = hexch64 + (unsigned)(par * 8 + grp) * 1536 + (unsigned)((l - 1) * 16) * 32;
            #pragma unroll
            for (int rep = 0; rep < 2; ++rep) {
                int i = tid + rep * 256;           // 512 u64 total
                int bi = i >> 5, kq = i & 31;
                u64 u = __hip_atomic_load(&isrc64[i], __ATOMIC_RELAXED, __HIP_MEMORY_SCOPE_AGENT);
                *(u64*)&inp_lds[bi * INPS + 4 * kq] = u;
            }
            __syncthreads();
            #pragma unroll
            for (int kt = 0; kt < 4; ++kt) {
                bf16x8 a = *(const bf16x8*)&inp_lds[lr * INPS + kt * 32 + lk * 8];
                acc = __builtin_amdgcn_mfma_f32_16x16x32_bf16(a, wfr[kt], acc, 0, 0, 0);
            }
        }

        // ================= cell =================
        #pragma unroll
        for (int r = 0; r < 4; ++r)
            gates_lds[w * 272 + (lk * 4 + r) * 17 + lr] = acc[r];
        __syncthreads();

        float ig = sigm(gates_lds[0 * 272 + bb * 17 + nn]);
        float fg = sigm(gates_lds[1 * 272 + bb * 17 + nn]);
        float gg = tanh_fast(gates_lds[2 * 272 + bb * 17 + nn]);
        float og = sigm(gates_lds[3 * 272 + bb * 17 + nn]);
        float cn = fg * c_reg + ig * gg;
        c_reg = cn;
        float hy = og * tanh_fast(cn);
        hsl[bb * 16 + nn] = f2bf(hy);
        if (t == S_LEN - 1) {
            long o = ((long)(l * BATCH + b0 + bb)) * NH + c * 16 + nn;
            out[o] = hy;
            out[(long)NL * BATCH * NH + o] = cn;
        }
        __syncthreads();

        // ================= publish: wave 0 only (vmcnt orders its own stores) =================
        if (tid < 64) {
            int row = tid >> 2, q = tid & 3;
            u64 v = ((const u64*)hsl)[tid];
            u64* dst = hexch64 + (unsigned)(par * 8 + grp) * 1536
                     + (unsigned)(l * 16 + row) * 32 + c * 4 + q;
            __hip_atomic_store(dst, v, __ATOMIC_RELAXED, __HIP_MEMORY_SCOPE_AGENT);
            asm volatile("s_waitcnt vmcnt(0)" ::: "memory");
            if (tid == 0)
                __hip_atomic_fetch_add(&flags[((unsigned)t * 3 + l) * 8 + grp], 1u,
                                       __ATOMIC_RELAXED, __HIP_MEMORY_SCOPE_AGENT);
        }
        // no barrier: next step's shared writes are all behind fresh barriers
    }
}

extern "C" void kernel_launch(void* const* d_in, const int* in_sizes, int n_in,
                              void* d_out, int out_size, void* d_ws, size_t ws_size,
                              hipStream_t stream) {
    const float* x     = (const float*)d_in[0];
    const float* lin_w = (const float*)d_in[1];
    const float* lin_b = (const float*)d_in[2];
    const float* W     = (const float*)d_in[3];
    const float* U     = (const float*)d_in[4];
    const float* G     = (const float*)d_in[5];
    float* out = (float*)d_out;

    short*    xp    = (short*)((char*)d_ws + XP_OFF);
    short*    Wp    = (short*)((char*)d_ws + WP_OFF);
    short*    Up    = (short*)((char*)d_ws + UP_OFF);
    unsigned* hexch = (unsigned*)((char*)d_ws + HX_OFF);
    unsigned* flags = (unsigned*)((char*)d_ws + FLAG_OFF);

    hipMemsetAsync(flags, 0, FLAG_SZ, stream);
    hipLaunchKernelGGL(xp_kernel,   dim3(8192), dim3(128), 0, stream, x, lin_w, lin_b, xp);
    hipLaunchKernelGGL(pack_kernel, dim3(384),  dim3(256), 0, stream, W, U, Wp, Up);
    hipLaunchKernelGGL(lstm_kernel, dim3(192),  dim3(256), 0, stream,
                       xp, Wp, Up, G, hexch, flags, out);
}